// Round 1
// baseline (284.996 us; speedup 1.0000x reference)
//
#include <hip/hip_runtime.h>
#include <math.h>

#define BDIM 64
#define HDIM 512
#define WDIM 512
#define KW 31
#define PAD 15
#define NPIX ((size_t)BDIM * HDIM * WDIM)

// ---------------- accumulator layout in d_ws (after hsum) ----------------
// acc[0]        : bce sum (double)
// acc[1..64]    : inter[b]
// acc[65..128]  : union[b]
#define NACC 129

__global__ void zero_acc_kernel(double* acc) {
    int i = threadIdx.x;
    if (i < NACC) acc[i] = 0.0;
}

// ---------------- pass 1: horizontal 31-tap box sum (zero padded) --------
// block = 256 threads = 4 rows x 64 threads; each thread produces 8 consecutive
// columns via sliding window out of an LDS row buffer.
__global__ void hbox_kernel(const float* __restrict__ mask, float* __restrict__ hsum) {
    __shared__ float rows[4 * WDIM];
    const int row0 = blockIdx.x * 4;              // global row index (b*H + y)
    const float* src = mask + (size_t)row0 * WDIM;

    for (int i = threadIdx.x; i < 4 * WDIM; i += 256) {
        rows[i] = src[i];
    }
    __syncthreads();

    const int r    = threadIdx.x >> 6;            // 0..3 row within block
    const int lane = threadIdx.x & 63;            // 0..63
    const int x0   = lane * 8;
    const float* rp = rows + r * WDIM;

    float s = 0.f;
    {
        int lo = x0 - PAD; if (lo < 0) lo = 0;
        int hi = x0 + PAD; if (hi > WDIM - 1) hi = WDIM - 1;
        for (int x = lo; x <= hi; ++x) s += rp[x];
    }

    float* dst = hsum + (size_t)(row0 + r) * WDIM;
    dst[x0] = s;
#pragma unroll
    for (int i = 1; i < 8; ++i) {
        int xa = x0 + i + PAD;       // new right edge
        int xr = x0 + i - PAD - 1;   // old left edge
        if (xa < WDIM) s += rp[xa];
        if (xr >= 0)   s -= rp[xr];
        dst[x0 + i] = s;
    }
}

// ---------------- pass 2: vertical sum + elementwise + reductions --------
// grid = (B, H/TH); block = 512 threads, one thread per column x.
#define TH 64

__global__ void fuse_kernel(const float* __restrict__ pred,
                            const float* __restrict__ mask,
                            const float* __restrict__ hsum,
                            double* __restrict__ acc) {
    const int b  = blockIdx.x;
    const int y0 = blockIdx.y * TH;
    const int x  = threadIdx.x;

    const size_t base = (size_t)b * HDIM * WDIM + x;
    const float* hb = hsum + base;
    const float* pb = pred + base;
    const float* mb = mask + base;

    // init vertical sliding sum over rows [y0-15, y0+15] clipped
    float vs = 0.f;
    {
        int lo = y0 - PAD; if (lo < 0) lo = 0;
        int hi = y0 + PAD; if (hi > HDIM - 1) hi = HDIM - 1;
        for (int y = lo; y <= hi; ++y) vs += hb[(size_t)y * WDIM];
    }

    float bce_acc = 0.f, inter_acc = 0.f, uni_acc = 0.f;

    for (int i = 0; i < TH; ++i) {
        const int y = y0 + i;
        const float box = vs * (1.0f / (KW * KW));
        const float m  = mb[(size_t)y * WDIM];
        const float pr = pb[(size_t)y * WDIM];

        const float weit = 1.f + 5.f * fabsf(box - m);
        const float bce  = fmaxf(pr, 0.f) - pr * m + log1pf(expf(-fabsf(pr)));
        const float p    = 1.f / (1.f + expf(-pr));

        bce_acc   += bce;
        inter_acc += p * m * weit;
        uni_acc   += (p + m) * weit;

        // slide window down one row: add y+16, remove y-15
        const int ya = y + PAD + 1;
        const int yr = y - PAD;
        if (ya < HDIM) vs += hb[(size_t)ya * WDIM];
        if (yr >= 0)   vs -= hb[(size_t)yr * WDIM];
    }

    // block reduction (512 threads = 8 waves)
    __shared__ float red[3][8];
#pragma unroll
    for (int off = 32; off > 0; off >>= 1) {
        bce_acc   += __shfl_down(bce_acc, off);
        inter_acc += __shfl_down(inter_acc, off);
        uni_acc   += __shfl_down(uni_acc, off);
    }
    const int wid = threadIdx.x >> 6;
    const int lid = threadIdx.x & 63;
    if (lid == 0) {
        red[0][wid] = bce_acc;
        red[1][wid] = inter_acc;
        red[2][wid] = uni_acc;
    }
    __syncthreads();
    if (threadIdx.x == 0) {
        float bs = 0.f, is = 0.f, us = 0.f;
#pragma unroll
        for (int w = 0; w < 8; ++w) { bs += red[0][w]; is += red[1][w]; us += red[2][w]; }
        atomicAdd(&acc[0],        (double)bs);
        atomicAdd(&acc[1 + b],    (double)is);
        atomicAdd(&acc[65 + b],   (double)us);
    }
}

// ---------------- finalize: wbce + mean_b(wiou_b) ------------------------
__global__ void finalize_kernel(const double* __restrict__ acc, float* __restrict__ out) {
    const int b = threadIdx.x;   // 0..63, one wave
    double inter = acc[1 + b];
    double uni   = acc[65 + b];
    double wiou  = 1.0 - (inter + 1.0) / (uni - inter + 1.0);
#pragma unroll
    for (int off = 32; off > 0; off >>= 1) wiou += __shfl_down(wiou, off);
    if (b == 0) {
        double wbce = acc[0] / (double)NPIX;
        out[0] = (float)(wbce + wiou / (double)BDIM);
    }
}

extern "C" void kernel_launch(void* const* d_in, const int* in_sizes, int n_in,
                              void* d_out, int out_size, void* d_ws, size_t ws_size,
                              hipStream_t stream) {
    const float* pred = (const float*)d_in[0];
    const float* mask = (const float*)d_in[1];
    float* out = (float*)d_out;

    float*  hsum = (float*)d_ws;                          // NPIX floats = 64 MiB
    double* acc  = (double*)((char*)d_ws + NPIX * sizeof(float));

    zero_acc_kernel<<<1, 256, 0, stream>>>(acc);

    // pass 1: 64*512 rows, 4 rows per block
    hbox_kernel<<<(BDIM * HDIM) / 4, 256, 0, stream>>>(mask, hsum);

    // pass 2
    dim3 grid2(BDIM, HDIM / TH);
    fuse_kernel<<<grid2, WDIM, 0, stream>>>(pred, mask, hsum, acc);

    finalize_kernel<<<1, 64, 0, stream>>>(acc, out);
}

// Round 2
// 249.176 us; speedup vs baseline: 1.1438x; 1.1438x over previous
//
#include <hip/hip_runtime.h>
#include <math.h>

#define BDIM 64
#define HDIM 512
#define WDIM 512
#define KW   31
#define PAD  15
#define INV_KK (1.0f / 961.0f)
#define TH   64                       // output rows per block
#define NPIX ((size_t)BDIM * HDIM * WDIM)

// acc[0]: bce sum; acc[1..64]: inter[b]; acc[65..128]: union[b]
#define NACC 129

__global__ void zero_acc_kernel(double* acc) {
    int i = threadIdx.x;
    if (i < NACC) acc[i] = 0.0;
}

// One block per (image, 64-row tile). 512 threads = one per column.
// Horizontal 31-box via wave prefix-sum; vertical 31-box via per-column
// sliding sum backed by a 32-row LDS ring (only owner thread touches a slot).
__global__ __launch_bounds__(512, 2)
void fused_kernel(const float* __restrict__ pred,
                  const float* __restrict__ mask,
                  double* __restrict__ acc) {
    __shared__ float pbuf[2][WDIM];   // prefix rows (double buffered)
    __shared__ float wtot[2][8];      // per-wave totals
    __shared__ float ring[32][WDIM];  // hsum history for vertical slide
    __shared__ float red[3][8];

    const int b    = blockIdx.x;
    const int y0   = blockIdx.y * TH;
    const int x    = threadIdx.x;
    const int lane = x & 63;
    const int wv   = x >> 6;

    const float* mbase = mask + (size_t)b * HDIM * WDIM;
    const float* pbase = pred + (size_t)b * HDIM * WDIM;

    float vs = 0.f;                   // vertical sliding sum for column x
    float bce_acc = 0.f, inter_acc = 0.f, uni_acc = 0.f;

    const int tstart = y0 - PAD;
    const int tend   = y0 + TH - 1 + PAD;

    for (int t = tstart; t <= tend; ++t) {
        const int par = t & 1;

        // ---- load mask row t (zero-padded outside [0,H)) ----
        float m = 0.f;
        if (t >= 0 && t < HDIM) m = mbase[(size_t)t * WDIM + x];

        // ---- wave-inclusive prefix sum across 64 lanes ----
        float p = m;
#pragma unroll
        for (int off = 1; off < 64; off <<= 1) {
            float tv = __shfl_up(p, off);
            p += (lane >= off) ? tv : 0.f;
        }
        pbuf[par][x] = p;
        if (lane == 63) wtot[par][wv] = p;
        __syncthreads();

        // ---- horizontal 31-box from prefix: P[x+15] - P[x-16] ----
        // span is 31 < 64, so the two indices differ by at most one wave;
        // carry difference is 0 or a single wave total.
        int ia = x + PAD; if (ia > WDIM - 1) ia = WDIM - 1;
        float hs;
        if (x <= PAD) {
            hs = pbuf[par][ia];               // ia <= 30 -> wave 0, carry 0
        } else {
            const int ib = x - PAD - 1;
            const float a  = pbuf[par][ia];
            const float bb = pbuf[par][ib];
            const int wa = ia >> 6, wb = ib >> 6;
            hs = a - bb + ((wa != wb) ? wtot[par][wb] : 0.f);
        }

        // ---- vertical sliding window ----
        vs += hs;
        if (t - KW >= tstart) vs -= ring[(t - KW) & 31][x];
        ring[t & 31][x] = hs;

        // ---- emit output row yo = t - 15 once window is complete ----
        if (t >= y0 + PAD) {
            const int yo = t - PAD;
            const float box = vs * INV_KK;
            const float mm = mbase[(size_t)yo * WDIM + x];  // L2-hot reload
            const float pr = pbase[(size_t)yo * WDIM + x];

            const float weit = 1.f + 5.f * fabsf(box - mm);
            const float e1   = __expf(-fabsf(pr));
            const float bce  = fmaxf(pr, 0.f) - pr * mm + __logf(1.f + e1);
            const float sp   = __builtin_amdgcn_rcpf(1.f + __expf(-pr));

            bce_acc   += bce;
            inter_acc += sp * mm * weit;
            uni_acc   += (sp + mm) * weit;
        }
        // no trailing sync needed: next iter writes pbuf[1-par]; its sync
        // separates this iter's reads from the t+2 overwrite of pbuf[par].
    }

    // ---- block reduction (8 waves) ----
#pragma unroll
    for (int off = 32; off > 0; off >>= 1) {
        bce_acc   += __shfl_down(bce_acc, off);
        inter_acc += __shfl_down(inter_acc, off);
        uni_acc   += __shfl_down(uni_acc, off);
    }
    if (lane == 0) {
        red[0][wv] = bce_acc;
        red[1][wv] = inter_acc;
        red[2][wv] = uni_acc;
    }
    __syncthreads();
    if (threadIdx.x == 0) {
        float bs = 0.f, is = 0.f, us = 0.f;
#pragma unroll
        for (int w = 0; w < 8; ++w) { bs += red[0][w]; is += red[1][w]; us += red[2][w]; }
        atomicAdd(&acc[0],      (double)bs);
        atomicAdd(&acc[1 + b],  (double)is);
        atomicAdd(&acc[65 + b], (double)us);
    }
}

__global__ void finalize_kernel(const double* __restrict__ acc, float* __restrict__ out) {
    const int b = threadIdx.x;   // one wave
    double inter = acc[1 + b];
    double uni   = acc[65 + b];
    double wiou  = 1.0 - (inter + 1.0) / (uni - inter + 1.0);
#pragma unroll
    for (int off = 32; off > 0; off >>= 1) wiou += __shfl_down(wiou, off);
    if (b == 0) {
        double wbce = acc[0] / (double)NPIX;
        out[0] = (float)(wbce + wiou / (double)BDIM);
    }
}

extern "C" void kernel_launch(void* const* d_in, const int* in_sizes, int n_in,
                              void* d_out, int out_size, void* d_ws, size_t ws_size,
                              hipStream_t stream) {
    const float* pred = (const float*)d_in[0];
    const float* mask = (const float*)d_in[1];
    float* out = (float*)d_out;
    double* acc = (double*)d_ws;

    zero_acc_kernel<<<1, 256, 0, stream>>>(acc);

    dim3 grid(BDIM, HDIM / TH);
    fused_kernel<<<grid, WDIM, 0, stream>>>(pred, mask, acc);

    finalize_kernel<<<1, 64, 0, stream>>>(acc, out);
}

// Round 3
// 217.319 us; speedup vs baseline: 1.3114x; 1.1466x over previous
//
#include <hip/hip_runtime.h>
#include <math.h>

#define BDIM 64
#define HDIM 512
#define WDIM 512
#define KW   31
#define PAD  15
#define INV_KK (1.0f / 961.0f)
#define TH   64                       // output rows per block
#define NPIX ((size_t)BDIM * HDIM * WDIM)

// acc[0]: bce sum; acc[1..64]: inter[b]; acc[65..128]: union[b]
#define NACC 129

__global__ void zero_acc_kernel(double* acc) {
    int i = threadIdx.x;
    if (i < NACC) acc[i] = 0.0;
}

// One block per (image, 64-row tile). 512 threads, 8 waves; each wave owns a
// 64-column strip and computes the horizontal 31-box entirely in-wave using a
// redundant ±15 halo (94 inputs in 2 regs/lane) + shfl prefix sums.
// NO barriers in the main loop. Vertical 31-box via LDS ring (thread-private
// slots). All global loads prefetched one row ahead.
__global__ __launch_bounds__(512, 2)
void fused_kernel(const float* __restrict__ pred,
                  const float* __restrict__ mask,
                  double* __restrict__ acc) {
    __shared__ float ring[32][WDIM];  // hsum history for vertical slide
    __shared__ float red[3][8];

    const int b    = blockIdx.x;
    const int y0   = blockIdx.y * TH;
    const int x    = threadIdx.x;     // output column
    const int lane = x & 63;
    const int wv   = x >> 6;
    const int s    = wv * 64;         // strip start column

    const float* mbase = mask + (size_t)b * HDIM * WDIM;
    const float* pbase = pred + (size_t)b * HDIM * WDIM;

    const int acol = s - 15 + lane;             // halo column for reg a
    const int bcol = s + 49 + lane;             // halo column for reg b
    const bool a_ok = (acol >= 0) && (acol < WDIM);
    const bool b_ok = (lane < 30) && (bcol < WDIM);

    const int tstart = y0 - PAD;
    const int tend   = y0 + TH - 1 + PAD;

    float vs = 0.f;
    float bce_acc = 0.f, inter_acc = 0.f, uni_acc = 0.f;

    // ---- prime prefetch for t = tstart ----
    float a_cur = 0.f, b_cur = 0.f;
    if (tstart >= 0) {                          // tstart could be <0 (y0==0)
        const float* rp = mbase + (size_t)tstart * WDIM;
        if (a_ok) a_cur = rp[acol];
        if (b_ok) b_cur = rp[bcol];
    }
    float em_m = 0.f, em_p = 0.f;               // emit-row values (prefetched)

    for (int t = tstart; t <= tend; ++t) {
        // ---- prefetch next row's halo + next emit row (consumed next iter) --
        float a_nxt = 0.f, b_nxt = 0.f;
        const int tn = t + 1;
        if (tn <= tend && tn >= 0 && tn < HDIM) {
            const float* rp = mbase + (size_t)tn * WDIM;
            if (a_ok) a_nxt = rp[acol];
            if (b_ok) b_nxt = rp[bcol];
        }
        float em_m_n = 0.f, em_p_n = 0.f;
        if (tn >= y0 + PAD && tn <= tend) {
            const size_t off = (size_t)(tn - PAD) * WDIM + x;
            em_m_n = mbase[off];
            em_p_n = pbase[off];
        }

        // ---- in-wave 94-element prefix sum ----
        float pa = a_cur;
#pragma unroll
        for (int off = 1; off < 64; off <<= 1) {
            float v = __shfl_up(pa, off);
            pa += (lane >= off) ? v : 0.f;
        }
        float pb = b_cur;
#pragma unroll
        for (int off = 1; off < 32; off <<= 1) {
            float v = __shfl_up(pb, off);
            pb += (lane >= off) ? v : 0.f;
        }
        const float atot = __shfl(pa, 63);

        // hs[col s+lane] = P[lane+30] - P[lane-1]
        const int hi_lane = (lane + 30) & 63;
        const float v1 = __shfl(pa, hi_lane);
        const float v2 = __shfl(pb, hi_lane);
        const float Phi = (lane <= 33) ? v1 : (atot + v2);
        const float v3 = __shfl(pa, (lane + 63) & 63);
        const float Plo = (lane >= 1) ? v3 : 0.f;
        const float hs = Phi - Plo;

        // ---- vertical sliding window (LDS ring, thread-private slot) ----
        vs += hs;
        if (t - KW >= tstart) vs -= ring[(t - KW) & 31][x];
        ring[t & 31][x] = hs;

        // ---- emit output row yo = t - 15 ----
        if (t >= y0 + PAD) {
            const float box  = vs * INV_KK;
            const float weit = 1.f + 5.f * fabsf(box - em_m);
            const float e1   = __expf(-fabsf(em_p));
            const float bce  = fmaxf(em_p, 0.f) - em_p * em_m + __logf(1.f + e1);
            const float sp   = __builtin_amdgcn_rcpf(1.f + __expf(-em_p));

            bce_acc   += bce;
            inter_acc += sp * em_m * weit;
            uni_acc   += (sp + em_m) * weit;
        }

        a_cur = a_nxt; b_cur = b_nxt;
        em_m = em_m_n; em_p = em_p_n;
    }

    // ---- block reduction (8 waves) ----
#pragma unroll
    for (int off = 32; off > 0; off >>= 1) {
        bce_acc   += __shfl_down(bce_acc, off);
        inter_acc += __shfl_down(inter_acc, off);
        uni_acc   += __shfl_down(uni_acc, off);
    }
    if (lane == 0) {
        red[0][wv] = bce_acc;
        red[1][wv] = inter_acc;
        red[2][wv] = uni_acc;
    }
    __syncthreads();
    if (threadIdx.x == 0) {
        float bs = 0.f, is = 0.f, us = 0.f;
#pragma unroll
        for (int w = 0; w < 8; ++w) { bs += red[0][w]; is += red[1][w]; us += red[2][w]; }
        atomicAdd(&acc[0],      (double)bs);
        atomicAdd(&acc[1 + b],  (double)is);
        atomicAdd(&acc[65 + b], (double)us);
    }
}

__global__ void finalize_kernel(const double* __restrict__ acc, float* __restrict__ out) {
    const int b = threadIdx.x;   // one wave
    double inter = acc[1 + b];
    double uni   = acc[65 + b];
    double wiou  = 1.0 - (inter + 1.0) / (uni - inter + 1.0);
#pragma unroll
    for (int off = 32; off > 0; off >>= 1) wiou += __shfl_down(wiou, off);
    if (b == 0) {
        double wbce = acc[0] / (double)NPIX;
        out[0] = (float)(wbce + wiou / (double)BDIM);
    }
}

extern "C" void kernel_launch(void* const* d_in, const int* in_sizes, int n_in,
                              void* d_out, int out_size, void* d_ws, size_t ws_size,
                              hipStream_t stream) {
    const float* pred = (const float*)d_in[0];
    const float* mask = (const float*)d_in[1];
    float* out = (float*)d_out;
    double* acc = (double*)d_ws;

    zero_acc_kernel<<<1, 256, 0, stream>>>(acc);

    dim3 grid(BDIM, HDIM / TH);
    fused_kernel<<<grid, WDIM, 0, stream>>>(pred, mask, acc);

    finalize_kernel<<<1, 64, 0, stream>>>(acc, out);
}

// Round 4
// 175.901 us; speedup vs baseline: 1.6202x; 1.2355x over previous
//
#include <hip/hip_runtime.h>
#include <math.h>

#define BDIM 64
#define HDIM 512
#define WDIM 512
#define KW   31
#define PAD  15
#define INV_KK (1.0f / 961.0f)
#define TH   64                       // output rows per block
#define NPIX ((size_t)BDIM * HDIM * WDIM)

// acc[0]: bce sum; acc[1..64]: inter[b]; acc[65..128]: union[b]
#define NACC 129

__global__ void zero_acc_kernel(double* acc) {
    int i = threadIdx.x;
    if (i < NACC) acc[i] = 0.0;
}

// ---- DPP helpers: VALU cross-lane (no LDS pipe, ~4cyc latency) ----------
template<int CTRL, int RMASK>
__device__ __forceinline__ float dpp_add(float p) {
    int t = __builtin_amdgcn_update_dpp(0, __builtin_bit_cast(int, p),
                                        CTRL, RMASK, 0xf, true);
    return p + __builtin_bit_cast(float, t);
}

// inclusive prefix sum over 64 lanes
__device__ __forceinline__ float wave_iscan(float p) {
    p = dpp_add<0x111, 0xf>(p);   // row_shr:1
    p = dpp_add<0x112, 0xf>(p);   // row_shr:2
    p = dpp_add<0x114, 0xf>(p);   // row_shr:4
    p = dpp_add<0x118, 0xf>(p);   // row_shr:8
    p = dpp_add<0x142, 0xa>(p);   // row_bcast:15 -> rows 1,3
    p = dpp_add<0x143, 0xc>(p);   // row_bcast:31 -> rows 2,3
    return p;
}

// inclusive prefix valid through lane 31 (we only use lanes 0..29)
__device__ __forceinline__ float wave_iscan30(float p) {
    p = dpp_add<0x111, 0xf>(p);
    p = dpp_add<0x112, 0xf>(p);
    p = dpp_add<0x114, 0xf>(p);
    p = dpp_add<0x118, 0xf>(p);
    p = dpp_add<0x142, 0xa>(p);
    return p;
}

// lane i <- lane i-1 (lane 0 -> 0): inclusive->exclusive shift
__device__ __forceinline__ float wave_shr1(float p) {
    int t = __builtin_amdgcn_update_dpp(0, __builtin_bit_cast(int, p),
                                        0x138 /*WAVE_SHR1*/, 0xf, 0xf, true);
    return __builtin_bit_cast(float, t);
}

// One block per (image, 64-row tile). 512 threads, 8 waves; each wave owns a
// 64-column strip, horizontal 31-box via DPP prefix scans over a redundant
// +/-15 halo. No barriers in the main loop. Vertical 31-box via LDS ring
// (thread-private slots). 2 rows per iteration; all global loads batched one
// iteration (2 rows) ahead so prefetch distance > HBM latency.
__global__ __launch_bounds__(512, 2)
void fused_kernel(const float* __restrict__ pred,
                  const float* __restrict__ mask,
                  double* __restrict__ acc) {
    __shared__ float ring[32][WDIM];  // hsum history for vertical slide
    __shared__ float red[3][8];

    const int b    = blockIdx.x;
    const int y0   = blockIdx.y * TH;
    const int x    = threadIdx.x;     // output column
    const int lane = x & 63;
    const int wv   = x >> 6;
    const int s    = wv * 64;         // strip start column

    const float* mbase = mask + (size_t)b * HDIM * WDIM;
    const float* pbase = pred + (size_t)b * HDIM * WDIM;

    const int acol = s - 15 + lane;             // halo column, reg a (pos 0..63)
    const int bcol = s + 49 + lane;             // halo column, reg b (pos 64..93)
    const bool a_ok = (acol >= 0) && (acol < WDIM);
    const bool b_ok = (lane < 30) && (bcol < WDIM);

    const int tstart = y0 - PAD;
    const int tend   = y0 + TH - 1 + PAD;       // 94 rows total

    float vs = 0.f;
    float bce_acc = 0.f, inter_acc = 0.f, uni_acc = 0.f;

    auto load_halo = [&](int row, float& A, float& B) {
        A = 0.f; B = 0.f;
        if (row >= 0 && row < HDIM) {
            const float* rp = mbase + (size_t)row * WDIM;
            if (a_ok) A = rp[acol];
            if (b_ok) B = rp[bcol];
        }
    };
    auto load_emit = [&](int row, float& M, float& P) {
        M = 0.f; P = 0.f;
        if (row >= y0 + PAD && row <= tend) {
            const size_t off = (size_t)(row - PAD) * WDIM + x;
            M = mbase[off];
            P = pbase[off];
        }
    };

    auto process = [&](int t, float A, float B, float M, float P) {
        float pa = wave_iscan(A);           // prefix over positions 0..63
        float pb = wave_iscan30(B);         // prefix over positions 64..93
        const float atot = __builtin_bit_cast(float,
            __builtin_amdgcn_readlane(__builtin_bit_cast(int, pa), 63));
        // hs[x] = P94[lane+30] - P94[lane-1]
        const float v1 = __shfl(pa, (lane + 30) & 63);
        const float v2 = __shfl(pb, (lane + 30) & 63);   // = pb[lane-34] for lane>=34
        const float Phi = (lane <= 33) ? v1 : (atot + v2);
        const float Plo = wave_shr1(pa);
        const float hs  = Phi - Plo;

        // vertical sliding window (LDS ring, thread-private slot, no sync)
        vs += hs;
        if (t - KW >= tstart) vs -= ring[(t - KW) & 31][x];
        ring[t & 31][x] = hs;

        if (t >= y0 + PAD) {                // emit output row yo = t - 15
            const float box  = vs * INV_KK;
            const float weit = 1.f + 5.f * fabsf(box - M);
            const float e1   = __expf(-fabsf(P));
            const float bce  = fmaxf(P, 0.f) - P * M + __logf(1.f + e1);
            const float sp   = __builtin_amdgcn_rcpf(1.f + __expf(-P));
            bce_acc   += bce;
            inter_acc += sp * M * weit;
            uni_acc   += (sp + M) * weit;
        }
    };

    // ---- prime: loads for the first iteration (rows tstart, tstart+1) ----
    float ca[2], cb[2], cm[2], cp[2];
    load_halo(tstart,     ca[0], cb[0]);
    load_halo(tstart + 1, ca[1], cb[1]);
    load_emit(tstart,     cm[0], cp[0]);
    load_emit(tstart + 1, cm[1], cp[1]);

    for (int t = tstart; t <= tend; t += 2) {   // 47 iterations, 2 rows each
        float na[2], nb[2], nm[2], nq[2];
        load_halo(t + 2, na[0], nb[0]);
        load_halo(t + 3, na[1], nb[1]);
        load_emit(t + 2, nm[0], nq[0]);
        load_emit(t + 3, nm[1], nq[1]);

        process(t,     ca[0], cb[0], cm[0], cp[0]);
        process(t + 1, ca[1], cb[1], cm[1], cp[1]);

        ca[0] = na[0]; ca[1] = na[1]; cb[0] = nb[0]; cb[1] = nb[1];
        cm[0] = nm[0]; cm[1] = nm[1]; cp[0] = nq[0]; cp[1] = nq[1];
    }

    // ---- block reduction (8 waves) ----
#pragma unroll
    for (int off = 32; off > 0; off >>= 1) {
        bce_acc   += __shfl_down(bce_acc, off);
        inter_acc += __shfl_down(inter_acc, off);
        uni_acc   += __shfl_down(uni_acc, off);
    }
    if (lane == 0) {
        red[0][wv] = bce_acc;
        red[1][wv] = inter_acc;
        red[2][wv] = uni_acc;
    }
    __syncthreads();
    if (threadIdx.x == 0) {
        float bs = 0.f, is = 0.f, us = 0.f;
#pragma unroll
        for (int w = 0; w < 8; ++w) { bs += red[0][w]; is += red[1][w]; us += red[2][w]; }
        atomicAdd(&acc[0],      (double)bs);
        atomicAdd(&acc[1 + b],  (double)is);
        atomicAdd(&acc[65 + b], (double)us);
    }
}

__global__ void finalize_kernel(const double* __restrict__ acc, float* __restrict__ out) {
    const int b = threadIdx.x;   // one wave
    double inter = acc[1 + b];
    double uni   = acc[65 + b];
    double wiou  = 1.0 - (inter + 1.0) / (uni - inter + 1.0);
#pragma unroll
    for (int off = 32; off > 0; off >>= 1) wiou += __shfl_down(wiou, off);
    if (b == 0) {
        double wbce = acc[0] / (double)NPIX;
        out[0] = (float)(wbce + wiou / (double)BDIM);
    }
}

extern "C" void kernel_launch(void* const* d_in, const int* in_sizes, int n_in,
                              void* d_out, int out_size, void* d_ws, size_t ws_size,
                              hipStream_t stream) {
    const float* pred = (const float*)d_in[0];
    const float* mask = (const float*)d_in[1];
    float* out = (float*)d_out;
    double* acc = (double*)d_ws;

    zero_acc_kernel<<<1, 256, 0, stream>>>(acc);

    dim3 grid(BDIM, HDIM / TH);
    fused_kernel<<<grid, WDIM, 0, stream>>>(pred, mask, acc);

    finalize_kernel<<<1, 64, 0, stream>>>(acc, out);
}